// Round 4
// baseline (896.089 us; speedup 1.0000x reference)
//
#include <hip/hip_runtime.h>
#include <hip/hip_bf16.h>

#define D_   1024
#define H_   16
#define HD_  64
#define B_   4
#define L_   2048
#define FFN_ 4096
#define M_   (B_ * L_)   // 8192

typedef __bf16 bf16x8 __attribute__((ext_vector_type(8)));
typedef float f32x4 __attribute__((ext_vector_type(4)));
typedef unsigned short ushort8 __attribute__((ext_vector_type(8)));
typedef unsigned short ushort4v __attribute__((ext_vector_type(4)));

__device__ inline unsigned short f2bf(float f) {
    unsigned int u = __float_as_uint(f);
    u += 0x7fff + ((u >> 16) & 1);   // RNE
    return (unsigned short)(u >> 16);
}
__device__ inline float bf2f(unsigned short u) {
    return __uint_as_float(((unsigned int)u) << 16);
}

// async global->LDS, 16B per lane. LDS dest: wave-uniform base + lane*16.
__device__ inline void gl_lds16(const unsigned short* g, unsigned short* l) {
    __builtin_amdgcn_global_load_lds(
        (const __attribute__((address_space(1))) unsigned int*)g,
        (__attribute__((address_space(3))) unsigned int*)l, 16, 0, 0);
}

// ---------------------------------------------------------------------------
// Transpose fp32 (K x N) -> bf16 (N x K), 64x64 tiles.
// ---------------------------------------------------------------------------
__global__ __launch_bounds__(256) void k_transpose_bf16(
    const float* __restrict__ in, unsigned short* __restrict__ out, int K, int N)
{
    __shared__ float tile[64][65];
    int k0 = blockIdx.y * 64, n0 = blockIdx.x * 64;
    int t = threadIdx.x;
    int r = t >> 2, cs = (t & 3) * 16;
    const float* src = in + (size_t)(k0 + r) * N + n0 + cs;
#pragma unroll
    for (int i = 0; i < 16; i += 4) {
        float4 v = *(const float4*)(src + i);
        tile[r][cs + i + 0] = v.x;
        tile[r][cs + i + 1] = v.y;
        tile[r][cs + i + 2] = v.z;
        tile[r][cs + i + 3] = v.w;
    }
    __syncthreads();
    unsigned short* dst = out + (size_t)(n0 + r) * K + k0 + cs;
#pragma unroll
    for (int i = 0; i < 16; ++i) dst[i] = f2bf(tile[cs + i][r]);
}

// ---------------------------------------------------------------------------
// Concat bq|bk|bv -> bqkv (3072)
// ---------------------------------------------------------------------------
__global__ void k_concat_bias(const float* __restrict__ bq, const float* __restrict__ bk,
                              const float* __restrict__ bv, float* __restrict__ out)
{
    int i = blockIdx.x * 256 + threadIdx.x;
    float v = (i < 1024) ? bq[i] : (i < 2048 ? bk[i - 1024] : bv[i - 2048]);
    out[i] = v;
}

// ---------------------------------------------------------------------------
// LayerNorm over D=1024, one block per row, out bf16.
// ---------------------------------------------------------------------------
__global__ __launch_bounds__(256) void k_layernorm(
    const float* __restrict__ x, const float* __restrict__ g, const float* __restrict__ be,
    unsigned short* __restrict__ out)
{
    int row = blockIdx.x;
    const float* xr = x + (size_t)row * D_;
    int t = threadIdx.x;
    float4 v = *(const float4*)(xr + t * 4);
    float s = v.x + v.y + v.z + v.w;
    float sq = v.x * v.x + v.y * v.y + v.z * v.z + v.w * v.w;
#pragma unroll
    for (int off = 32; off >= 1; off >>= 1) {
        s  += __shfl_down(s, off);
        sq += __shfl_down(sq, off);
    }
    __shared__ float ps[4], psq[4];
    int w = t >> 6;
    if ((t & 63) == 0) { ps[w] = s; psq[w] = sq; }
    __syncthreads();
    float tot  = ps[0] + ps[1] + ps[2] + ps[3];
    float totq = psq[0] + psq[1] + psq[2] + psq[3];
    float mu  = tot * (1.f / D_);
    float var = totq * (1.f / D_) - mu * mu;
    float inv = rsqrtf(var + 1e-5f);
    float4 gv = *(const float4*)(g + t * 4);
    float4 bv = *(const float4*)(be + t * 4);
    ushort4v o;
    o[0] = f2bf((v.x - mu) * inv * gv.x + bv.x);
    o[1] = f2bf((v.y - mu) * inv * gv.y + bv.y);
    o[2] = f2bf((v.z - mu) * inv * gv.z + bv.z);
    o[3] = f2bf((v.w - mu) * inv * gv.w + bv.w);
    *(ushort4v*)(out + (size_t)row * D_ + t * 4) = o;
}

// ---------------------------------------------------------------------------
// Big-tile GEMM: C(MxN) = A(MxK,bf16) * Bt(NxK,bf16)^T + bias [+resid] [relu]
// BM=256 x BN(128|256) tile, BK=32, 512 thr = 8 waves (WGM x WGN), wave owns
// (256/WGM) x (BN/WGN). Same proven 2-phase structure as before:
// global_load_lds(16B) into LINEAR double-buffered LDS, ONE barrier per
// K-step (drains vmcnt), next-tile DMA issued right after the barrier.
// Rationale (R4): 128^2 tiles staged ~3.1GB/iter from L2/L3 (B-panels > 4MB
// L2) -> GEMMs ran ~330 TF. BM=256 halves staged traffic per FLOP and 4x's
// MFMA per barrier-pair. Grids chosen to quantize exactly (1-3 full rounds
// at 1 block/CU). 1D grid, XCD-chunked swizzle (grid % 8 == 0 always).
// ---------------------------------------------------------------------------
template <int BN, int WGN, bool OUT_BF16, bool RELU, bool RESID>
__global__ __launch_bounds__(512, 2) void k_gemm2(
    const unsigned short* __restrict__ A, const unsigned short* __restrict__ Bt,
    const float* __restrict__ bias, const float* __restrict__ resid,
    void* __restrict__ Cout, int M, int N, int K)
{
    constexpr int WGM = 8 / WGN;
    constexpr int MS = 256 / WGM;      // wave M span (128 or 64)
    constexpr int NS = BN / WGN;       // wave N span (64)
    constexpr int MI = MS / 16;
    constexpr int NI = NS / 16;

    __shared__ unsigned short sA[2][256 * 32];   // linear, row stride 32 elems
    __shared__ unsigned short sB[2][BN * 32];

    // XCD-chunked bijective swizzle (nwg always % 8 == 0)
    int nwg = gridDim.x, flat = blockIdx.x;
    int wg = (flat & 7) * (nwg >> 3) + (flat >> 3);
    int gx = N / BN;
    int m0 = (wg / gx) * 256, n0 = (wg % gx) * BN;

    int tid = threadIdx.x, lane = tid & 63, wv = tid >> 6;
    int wr = wv / WGN, wc = wv % WGN;
    int wm = wr * MS, wn = wc * NS;
    int lr = lane & 15, qd = lane >> 4;

    f32x4 acc[MI][NI] = {};

    // staging: wave wv covers rows [wv*16, wv*16+16) of each 128-row half.
    // one gl_lds16 = 64 lanes x 16B = 16 rows x 64B (BK=32 bf16), linear.
    int srow = lane >> 2, scol = (lane & 3) * 8;
    const unsigned short* gA0 = A + (size_t)(m0 + wv * 16 + srow) * K + scol;
    const unsigned short* gA1 = gA0 + (size_t)128 * K;
    const unsigned short* gB0 = Bt + (size_t)(n0 + wv * 16 + srow) * K + scol;
    const unsigned short* gB1 = gB0 + (size_t)128 * K;
    int lb0 = (wv * 16) * 32, lb1 = (wv * 16 + 128) * 32;

    // prologue: stage tile 0 into buf 0
    gl_lds16(gA0, &sA[0][lb0]);
    gl_lds16(gA1, &sA[0][lb1]);
    gl_lds16(gB0, &sB[0][lb0]);
    if constexpr (BN == 256) gl_lds16(gB1, &sB[0][lb1]);

    int nk = K >> 5;
    for (int ki = 0; ki < nk; ++ki) {
        int cur = ki & 1;
        __syncthreads();   // drains vmcnt(0): buf[cur] ready; ends reads of buf[cur^1]
        if (ki + 1 < nk) {
            int k1 = (ki + 1) << 5;
            gl_lds16(gA0 + k1, &sA[cur ^ 1][lb0]);
            gl_lds16(gA1 + k1, &sA[cur ^ 1][lb1]);
            gl_lds16(gB0 + k1, &sB[cur ^ 1][lb0]);
            if constexpr (BN == 256) gl_lds16(gB1 + k1, &sB[cur ^ 1][lb1]);
        }
        bf16x8 af[MI], bfr[NI];
#pragma unroll
        for (int i = 0; i < MI; ++i)
            af[i] = *(const bf16x8*)(&sA[cur][(wm + i * 16 + lr) * 32 + qd * 8]);
#pragma unroll
        for (int i = 0; i < NI; ++i)
            bfr[i] = *(const bf16x8*)(&sB[cur][(wn + i * 16 + lr) * 32 + qd * 8]);
        __builtin_amdgcn_s_setprio(1);
#pragma unroll
        for (int mi = 0; mi < MI; ++mi)
#pragma unroll
            for (int ni = 0; ni < NI; ++ni)
                acc[mi][ni] = __builtin_amdgcn_mfma_f32_16x16x32_bf16(
                    af[mi], bfr[ni], acc[mi][ni], 0, 0, 0);
        __builtin_amdgcn_s_setprio(0);
    }

#pragma unroll
    for (int ni = 0; ni < NI; ++ni) {
        int col = n0 + wn + ni * 16 + lr;
        float bvv = bias[col];
#pragma unroll
        for (int mi = 0; mi < MI; ++mi) {
#pragma unroll
            for (int r = 0; r < 4; ++r) {
                int row = m0 + wm + mi * 16 + qd * 4 + r;
                float v = acc[mi][ni][r] + bvv;
                if (RELU) v = fmaxf(v, 0.f);
                if (RESID) v += resid[(size_t)row * N + col];
                if (OUT_BF16)
                    ((unsigned short*)Cout)[(size_t)row * N + col] = f2bf(v);
                else
                    ((float*)Cout)[(size_t)row * N + col] = v;
            }
        }
    }
}

// ---------------------------------------------------------------------------
// Flash attention, MFMA. 1D grid of 2048 blocks, XCD-swizzled so the 4 batch
// blocks sharing the same (h, q-tile) rpb rows land on the same XCD, and the
// longest q-tiles dispatch first. 256 thr = 4 waves, wave w owns q-rows
// [w*16, w*16+16). Q in registers. K/V staged T14-style. V^T XOR-swizzled.
// Causal mask applied only on the diagonal tile (kt == qt).
// __launch_bounds__(256,4): bound 6 forced VGPR 40 -> 1.2GB scratch spill (R2).
// qkv: [M][3072] bf16 (q|k|v each h*64+d). out: [M][1024] bf16.
// ---------------------------------------------------------------------------
__global__ __launch_bounds__(256, 4) void k_attn(
    const unsigned short* __restrict__ qkv, const float* __restrict__ rpb,
    unsigned short* __restrict__ out)
{
    __shared__ unsigned short Ks[64 * 72];
    __shared__ unsigned short Vt[64 * 64];   // element (d,key) at d*64 + (key ^ (swz(d)<<3))
    __shared__ unsigned short Sp[64 * 72];

    // grid swizzle: flat = hi*32 + b*8 + xcd ; g = hi*8 + xcd in 0..511
    int flat = blockIdx.x;
    int xcd = flat & 7, b = (flat >> 3) & 3, hi = flat >> 5;
    int g = hi * 8 + xcd;
    int h = g & 15;
    int qt = 31 - (g >> 4);          // longest blocks first
    int q0 = qt * 64;

    int t = threadIdx.x, lane = t & 63, w = t >> 6;
    int lr = lane & 15, qd = lane >> 4;
    int sr = t >> 2, ss = (t & 3) * 16;
    int bL = b * L_;

    // Q fragments in registers (each wave reads only its own 16 rows)
    bf16x8 aq[2];
    {
        const unsigned short* qsrc =
            qkv + (size_t)(bL + q0 + w * 16 + lr) * 3072 + h * 64 + qd * 8;
        aq[0] = *(const bf16x8*)qsrc;
        aq[1] = *(const bf16x8*)(qsrc + 32);
    }

    f32x4 oacc[4] = {};
    float m_r[4], l_r[4];
#pragma unroll
    for (int r = 0; r < 4; ++r) { m_r[r] = -1e30f; l_r[r] = 0.f; }

    int qrow_base = q0 + w * 16 + qd * 4;
    int ntile = qt + 1;

    // T14 staging registers (K row chunk + V row chunk, 16 elems each)
    ushort8 krA, krB, vrA, vrB;
    {
        const unsigned short* kb_ = qkv + (size_t)(bL + sr) * 3072 + 1024 + h * 64 + ss;
        krA = *(const ushort8*)kb_;  krB = *(const ushort8*)(kb_ + 8);
        vrA = *(const ushort8*)(kb_ + 1024); vrB = *(const ushort8*)(kb_ + 1032);
    }

    for (int kt = 0; kt < ntile; ++kt) {
        int k0 = kt * 64;
        if (kt) __syncthreads();     // all waves done reading previous tile's LDS

        // ---- stage K rows (vectorized, conflict-free) ----
        *(ushort8*)(Ks + sr * 72 + ss)     = krA;
        *(ushort8*)(Ks + sr * 72 + ss + 8) = krB;

        // ---- stage V^T: packed key-pairs into swizzled layout ----
        {
            int role = sr & 1;           // 0: handles d=ss..ss+7, 1: d=ss+8..ss+15
            int srp  = sr & ~1;          // even key of the pair
#pragma unroll
            for (int i = 0; i < 8; ++i) {
                // even-role sends vrB (partner needs it), odd-role sends vrA
                int sendv = role ? (int)(unsigned int)vrA[i] : (int)(unsigned int)vrB[i];
                int got = __shfl_xor(sendv, 4);
                int d = role ? (ss + 8 + i) : (ss + i);
                unsigned short lo = role ? (unsigned short)got : vrA[i]; // key srp
                unsigned short hi = role ? vrB[i] : (unsigned short)got; // key srp+1
                int swz = (d ^ (d >> 3)) & 7;
                unsigned int u = (unsigned int)lo | ((unsigned int)hi << 16);
                *(unsigned int*)(Vt + d * 64 + (srp ^ (swz << 3))) = u;
            }
        }
        __syncthreads();             // tile kt staged

        // ---- prefetch rpb for this tile (issued before next-tile K/V so the
        //      softmax waits vmcnt(4), leaving the K/V loads in flight) ----
        float rv[4][4];
        {
            const float* rpb_base = rpb + ((size_t)h * L_ + qrow_base) * L_ + k0;
#pragma unroll
            for (int r = 0; r < 4; ++r)
#pragma unroll
                for (int nt = 0; nt < 4; ++nt)
                    rv[r][nt] = rpb_base[(size_t)r * L_ + nt * 16 + lr];
        }

        // ---- issue next tile's K/V global loads (land during compute) ----
        if (kt + 1 < ntile) {
            const unsigned short* kb_ =
                qkv + (size_t)(bL + k0 + 64 + sr) * 3072 + 1024 + h * 64 + ss;
            krA = *(const ushort8*)kb_;  krB = *(const ushort8*)(kb_ + 8);
            vrA = *(const ushort8*)(kb_ + 1024); vrB = *(const ushort8*)(kb_ + 1032);
        }

        // ---- S = Q K^T (16 q-rows x 64 keys per wave) ----
        f32x4 sc4[4] = {};
        __builtin_amdgcn_s_setprio(1);
#pragma unroll
        for (int ks = 0; ks < 2; ++ks) {
#pragma unroll
            for (int nt = 0; nt < 4; ++nt) {
                bf16x8 bk8 = *(const bf16x8*)(Ks + (nt * 16 + lr) * 72 + ks * 32 + qd * 8);
                sc4[nt] = __builtin_amdgcn_mfma_f32_16x16x32_bf16(aq[ks], bk8, sc4[nt], 0, 0, 0);
            }
        }
        __builtin_amdgcn_s_setprio(0);

        // ---- online softmax (state replicated over the 16 lanes of each quad) ----
        bool last = (kt == qt);      // only the diagonal tile needs the causal mask
        float pvv[4][4], mx[4];
#pragma unroll
        for (int r = 0; r < 4; ++r) {
            mx[r] = -1e30f;
#pragma unroll
            for (int nt = 0; nt < 4; ++nt) {
                float sv = sc4[nt][r] * 0.125f + rv[r][nt];
                if (last && (k0 + nt * 16 + lr > qrow_base + r)) sv = -1e30f;
                pvv[r][nt] = sv;
                mx[r] = fmaxf(mx[r], sv);
            }
        }
#pragma unroll
        for (int r = 0; r < 4; ++r) {
            mx[r] = fmaxf(mx[r], __shfl_xor(mx[r], 1));
            mx[r] = fmaxf(mx[r], __shfl_xor(mx[r], 2));
            mx[r] = fmaxf(mx[r], __shfl_xor(mx[r], 4));
            mx[r] = fmaxf(mx[r], __shfl_xor(mx[r], 8));
        }
#pragma unroll
        for (int r = 0; r < 4; ++r) {
            float mnew  = fmaxf(m_r[r], mx[r]);
            float alpha = __expf(m_r[r] - mnew);
            float psum = 0.f;
#pragma unroll
            for (int nt = 0; nt < 4; ++nt) {
                float p = __expf(pvv[r][nt] - mnew);
                psum += p;
                Sp[(w * 16 + qd * 4 + r) * 72 + nt * 16 + lr] = f2bf(p);
            }
            psum += __shfl_xor(psum, 1);
            psum += __shfl_xor(psum, 2);
            psum += __shfl_xor(psum, 4);
            psum += __shfl_xor(psum, 8);
            l_r[r] = l_r[r] * alpha + psum;
            m_r[r] = mnew;
            oacc[0][r] *= alpha; oacc[1][r] *= alpha;
            oacc[2][r] *= alpha; oacc[3][r] *= alpha;
        }

        // ---- O += P V  (A = P from Sp, B = swizzled Vt) ----
        __builtin_amdgcn_s_setprio(1);
#pragma unroll
        for (int ks = 0; ks < 2; ++ks) {
            bf16x8 ap = *(const bf16x8*)(Sp + (w * 16 + lr) * 72 + ks * 32 + qd * 8);
#pragma unroll
            for (int dt = 0; dt < 4; ++dt) {
                int d = dt * 16 + lr;
                int swz = (d ^ (d >> 3)) & 7;
                bf16x8 bv8 = *(const bf16x8*)(Vt + d * 64 + ((ks * 32 + qd * 8) ^ (swz << 3)));
                oacc[dt] = __builtin_amdgcn_mfma_f32_16x16x32_bf16(ap, bv8, oacc[dt], 0, 0, 0);
            }
        }
        __builtin_amdgcn_s_setprio(0);
    }

#pragma unroll
    for (int r = 0; r < 4; ++r) {
        float linv = 1.f / l_r[r];
        int qrow = q0 + w * 16 + qd * 4 + r;
        unsigned short* dst = out + (size_t)(bL + qrow) * 1024 + h * 64;
#pragma unroll
        for (int dt = 0; dt < 4; ++dt)
            dst[dt * 16 + lr] = f2bf(oacc[dt][r] * linv);
    }
}

// ---------------------------------------------------------------------------
extern "C" void kernel_launch(void* const* d_in, const int* in_sizes, int n_in,
                              void* d_out, int out_size, void* d_ws, size_t ws_size,
                              hipStream_t stream)
{
    const float* x   = (const float*)d_in[0];
    const float* rpb = (const float*)d_in[1];
    const float* wq  = (const float*)d_in[2];
    const float* bq  = (const float*)d_in[3];
    const float* wk  = (const float*)d_in[4];
    const float* bk  = (const float*)d_in[5];
    const float* wv  = (const float*)d_in[6];
    const float* bv  = (const float*)d_in[7];
    const float* wo  = (const float*)d_in[8];
    const float* bo  = (const float*)d_in[9];
    const float* g1  = (const float*)d_in[10];
    const float* be1 = (const float*)d_in[11];
    const float* g2  = (const float*)d_in[12];
    const float* be2 = (const float*)d_in[13];
    const float* w1  = (const float*)d_in[14];
    const float* bf1 = (const float*)d_in[15];
    const float* w2  = (const float*)d_in[16];
    const float* bf2 = (const float*)d_in[17];
    float* out = (float*)d_out;
    char* ws = (char*)d_ws;

    // workspace layout (bytes); h overlays xn1+qkv (both dead by FFN1)
    unsigned short* xn1   = (unsigned short*)(ws + 0);
    unsigned short* qkv   = (unsigned short*)(ws + 16777216);
    unsigned short* attno = (unsigned short*)(ws + 0);
    unsigned short* hbuf  = (unsigned short*)(ws + 0);
    float*          xmid  = (float*)(ws + 67108864);
    unsigned short* xn2   = (unsigned short*)(ws + 100663296);
    unsigned short* wqkvT = (unsigned short*)(ws + 117440512);
    unsigned short* woT   = (unsigned short*)(ws + 123731968);
    unsigned short* w1T   = (unsigned short*)(ws + 125829120);
    unsigned short* w2T   = (unsigned short*)(ws + 134217728);
    float*          bqkv  = (float*)(ws + 142606336);

    // weight prep (fp32 KxN -> bf16 NxK)
    k_transpose_bf16<<<dim3(16, 16), 256, 0, stream>>>(wq, wqkvT,                1024, 1024);
    k_transpose_bf16<<<dim3(16, 16), 256, 0, stream>>>(wk, wqkvT + 1024 * 1024,  1024, 1024);
    k_transpose_bf16<<<dim3(16, 16), 256, 0, stream>>>(wv, wqkvT + 2048 * 1024,  1024, 1024);
    k_transpose_bf16<<<dim3(16, 16), 256, 0, stream>>>(wo, woT,                  1024, 1024);
    k_transpose_bf16<<<dim3(64, 16), 256, 0, stream>>>(w1, w1T,                  1024, 4096);
    k_transpose_bf16<<<dim3(16, 64), 256, 0, stream>>>(w2, w2T,                  4096, 1024);
    k_concat_bias<<<12, 256, 0, stream>>>(bq, bk, bv, bqkv);

    // LN1 -> xn1 (bf16)
    k_layernorm<<<M_, 256, 0, stream>>>(x, g1, be1, xn1);
    // fused QKV projection: (8192x1024) x (1024x3072), 256x128 tiles, 768 wgs
    k_gemm2<128, 2, true, false, false><<<dim3(768), 512, 0, stream>>>(
        xn1, wqkvT, bqkv, nullptr, qkv, M_, 3072, 1024);
    // attention -> attno (bf16, [M][1024])
    k_attn<<<dim3(2048), 256, 0, stream>>>(qkv, rpb, attno);
    // output proj + residual -> xmid (fp32), 256x128 tiles, 256 wgs
    k_gemm2<128, 2, false, false, true><<<dim3(256), 512, 0, stream>>>(
        attno, woT, bo, x, xmid, M_, 1024, 1024);
    // LN2 -> xn2 (bf16)
    k_layernorm<<<M_, 256, 0, stream>>>(xmid, g2, be2, xn2);
    // FFN1 + ReLU -> h (bf16), 256x256 tiles, 512 wgs
    k_gemm2<256, 4, true, true, false><<<dim3(512), 512, 0, stream>>>(
        xn2, w1T, bf1, nullptr, hbuf, M_, 4096, 1024);
    // FFN2 + residual -> out (fp32), 256x128 tiles, 256 wgs
    k_gemm2<128, 2, false, false, true><<<dim3(256), 512, 0, stream>>>(
        hbuf, w2T, bf2, xmid, out, M_, 1024, 4096);
}

// Round 5
// 846.384 us; speedup vs baseline: 1.0587x; 1.0587x over previous
//
#include <hip/hip_runtime.h>
#include <hip/hip_bf16.h>

#define D_   1024
#define H_   16
#define HD_  64
#define B_   4
#define L_   2048
#define FFN_ 4096
#define M_   (B_ * L_)   // 8192

typedef __bf16 bf16x8 __attribute__((ext_vector_type(8)));
typedef float f32x4 __attribute__((ext_vector_type(4)));
typedef unsigned short ushort8 __attribute__((ext_vector_type(8)));
typedef unsigned short ushort4v __attribute__((ext_vector_type(4)));

__device__ inline unsigned short f2bf(float f) {
    unsigned int u = __float_as_uint(f);
    u += 0x7fff + ((u >> 16) & 1);   // RNE
    return (unsigned short)(u >> 16);
}

// async global->LDS, 16B per lane. LDS dest: wave-uniform base + lane*16.
__device__ inline void gl_lds16(const unsigned short* g, unsigned short* l) {
    __builtin_amdgcn_global_load_lds(
        (const __attribute__((address_space(1))) unsigned int*)g,
        (__attribute__((address_space(3))) unsigned int*)l, 16, 0, 0);
}

// ---------------------------------------------------------------------------
// Transpose fp32 (K x N) -> bf16 (N x K), 64x64 tiles.
// ---------------------------------------------------------------------------
__global__ __launch_bounds__(256) void k_transpose_bf16(
    const float* __restrict__ in, unsigned short* __restrict__ out, int K, int N)
{
    __shared__ float tile[64][65];
    int k0 = blockIdx.y * 64, n0 = blockIdx.x * 64;
    int t = threadIdx.x;
    int r = t >> 2, cs = (t & 3) * 16;
    const float* src = in + (size_t)(k0 + r) * N + n0 + cs;
#pragma unroll
    for (int i = 0; i < 16; i += 4) {
        float4 v = *(const float4*)(src + i);
        tile[r][cs + i + 0] = v.x;
        tile[r][cs + i + 1] = v.y;
        tile[r][cs + i + 2] = v.z;
        tile[r][cs + i + 3] = v.w;
    }
    __syncthreads();
    unsigned short* dst = out + (size_t)(n0 + r) * K + k0 + cs;
#pragma unroll
    for (int i = 0; i < 16; ++i) dst[i] = f2bf(tile[cs + i][r]);
}

// ---------------------------------------------------------------------------
// Concat bq|bk|bv -> bqkv (3072)
// ---------------------------------------------------------------------------
__global__ void k_concat_bias(const float* __restrict__ bq, const float* __restrict__ bk,
                              const float* __restrict__ bv, float* __restrict__ out)
{
    int i = blockIdx.x * 256 + threadIdx.x;
    float v = (i < 1024) ? bq[i] : (i < 2048 ? bk[i - 1024] : bv[i - 2048]);
    out[i] = v;
}

// ---------------------------------------------------------------------------
// LayerNorm over D=1024, one block per row, out bf16.
// ---------------------------------------------------------------------------
__global__ __launch_bounds__(256) void k_layernorm(
    const float* __restrict__ x, const float* __restrict__ g, const float* __restrict__ be,
    unsigned short* __restrict__ out)
{
    int row = blockIdx.x;
    const float* xr = x + (size_t)row * D_;
    int t = threadIdx.x;
    float4 v = *(const float4*)(xr + t * 4);
    float s = v.x + v.y + v.z + v.w;
    float sq = v.x * v.x + v.y * v.y + v.z * v.z + v.w * v.w;
#pragma unroll
    for (int off = 32; off >= 1; off >>= 1) {
        s  += __shfl_down(s, off);
        sq += __shfl_down(sq, off);
    }
    __shared__ float ps[4], psq[4];
    int w = t >> 6;
    if ((t & 63) == 0) { ps[w] = s; psq[w] = sq; }
    __syncthreads();
    float tot  = ps[0] + ps[1] + ps[2] + ps[3];
    float totq = psq[0] + psq[1] + psq[2] + psq[3];
    float mu  = tot * (1.f / D_);
    float var = totq * (1.f / D_) - mu * mu;
    float inv = rsqrtf(var + 1e-5f);
    float4 gv = *(const float4*)(g + t * 4);
    float4 bv = *(const float4*)(be + t * 4);
    ushort4v o;
    o[0] = f2bf((v.x - mu) * inv * gv.x + bv.x);
    o[1] = f2bf((v.y - mu) * inv * gv.y + bv.y);
    o[2] = f2bf((v.z - mu) * inv * gv.z + bv.z);
    o[3] = f2bf((v.w - mu) * inv * gv.w + bv.w);
    *(ushort4v*)(out + (size_t)row * D_ + t * 4) = o;
}

// ---------------------------------------------------------------------------
// GEMM v3: C(MxN) = A(MxK,bf16) * Bt(NxK,bf16)^T + bias [+resid] [relu]
// BK=64, LDS row = 64 elems (128B). 2-phase dbuf, ONE __syncthreads per
// K-step (drain accepted), next-tile DMA issued right after the barrier.
// R4 lesson: efficiency ~ MFMA_cyc/(MFMA_cyc+drain); BK=64 doubles MFMA per
// drain (m248: 2ph 256^2 @K=1024 = 655-682 TF).
// LDS swizzle (rule #21, both-sides): DMA dest is linear; the GLOBAL source
// col is pre-swizzled chunk c^(row&7) (stays within one 128B segment ->
// coalesced); ds_read applies the same XOR. Gives uniform 8-lanes-per-16B-
// slot distribution (the wave64 b128 minimum) instead of 4 hot slots.
// Grids: 1D, XCD-chunked bijective swizzle (all grids % 8 == 0).
// ---------------------------------------------------------------------------
template <int BM, int BN, int WM, int WN, bool OUT_BF16, bool RELU, bool RESID>
__global__ __launch_bounds__(WM * WN * 64, 2) void k_gemm3(
    const unsigned short* __restrict__ A, const unsigned short* __restrict__ Bt,
    const float* __restrict__ bias, const float* __restrict__ resid,
    void* __restrict__ Cout, int M, int N, int K)
{
    constexpr int NW  = WM * WN;          // waves per block
    constexpr int MS  = BM / WM;          // wave M span
    constexpr int NS  = BN / WN;          // wave N span
    constexpr int MI  = MS / 16;
    constexpr int NI  = NS / 16;
    constexpr int APW = BM / (8 * NW);    // A stage-insts per wave (8 rows each)
    constexpr int BPW = BN / (8 * NW);

    __shared__ unsigned short sA[2][BM * 64];
    __shared__ unsigned short sB[2][BN * 64];

    // XCD-chunked bijective swizzle (nwg % 8 == 0 for all our grids)
    int nwg = gridDim.x, flat = blockIdx.x;
    int wg = (flat & 7) * (nwg >> 3) + (flat >> 3);
    int gx = N / BN;
    int m0 = (wg / gx) * BM, n0 = (wg % gx) * BN;

    int tid = threadIdx.x, lane = tid & 63, wv = tid >> 6;
    int wr = wv / WN, wc = wv % WN;
    int wm = wr * MS, wn = wc * NS;
    int lr = lane & 15, qd = lane >> 4;

    f32x4 acc[MI][NI] = {};

    // staging geometry: one inst = 64 lanes x 16B = 8 rows x 128B (64 elems).
    // lane covers row r8 = lane>>3, linear chunk c8 = lane&7; it FETCHES
    // global chunk c8 ^ (r8&7) so LDS[row][c] holds global[row][c^(row&7)].
    int r8 = lane >> 3, c8 = lane & 7;
    int csw = ((c8 ^ (r8 & 7)) * 8);     // elem col within the 64-col window
    const unsigned short* gA[APW];
    const unsigned short* gB[BPW];
    int laA[APW], laB[BPW];
#pragma unroll
    for (int s = 0; s < APW; ++s) {
        int rl = wv * 8 * APW + s * 8;   // wave-uniform base row
        gA[s]  = A + (size_t)(m0 + rl + r8) * K + csw;
        laA[s] = rl * 64;
    }
#pragma unroll
    for (int s = 0; s < BPW; ++s) {
        int rl = wv * 8 * BPW + s * 8;
        gB[s]  = Bt + (size_t)(n0 + rl + r8) * K + csw;
        laB[s] = rl * 64;
    }

    // prologue: stage tile 0 into buf 0
#pragma unroll
    for (int s = 0; s < APW; ++s) gl_lds16(gA[s], &sA[0][laA[s]]);
#pragma unroll
    for (int s = 0; s < BPW; ++s) gl_lds16(gB[s], &sB[0][laB[s]]);

    int nk = K >> 6;
    for (int ki = 0; ki < nk; ++ki) {
        int cur = ki & 1;
        __syncthreads();   // drains vmcnt: buf[cur] ready; ends reads of buf[cur^1]
        if (ki + 1 < nk) {
            int k1 = (ki + 1) << 6;
#pragma unroll
            for (int s = 0; s < APW; ++s) gl_lds16(gA[s] + k1, &sA[cur ^ 1][laA[s]]);
#pragma unroll
            for (int s = 0; s < BPW; ++s) gl_lds16(gB[s] + k1, &sB[cur ^ 1][laB[s]]);
        }
#pragma unroll
        for (int ks = 0; ks < 2; ++ks) {
            bf16x8 af[MI], bfr[NI];
#pragma unroll
            for (int i = 0; i < MI; ++i) {
                int row = wm + i * 16 + lr;
                int p = ((ks * 4 + qd) ^ (lr & 7)) * 8;
                af[i] = *(const bf16x8*)(&sA[cur][row * 64 + p]);
            }
#pragma unroll
            for (int i = 0; i < NI; ++i) {
                int row = wn + i * 16 + lr;
                int p = ((ks * 4 + qd) ^ (lr & 7)) * 8;
                bfr[i] = *(const bf16x8*)(&sB[cur][row * 64 + p]);
            }
            __builtin_amdgcn_s_setprio(1);
#pragma unroll
            for (int mi = 0; mi < MI; ++mi)
#pragma unroll
                for (int ni = 0; ni < NI; ++ni)
                    acc[mi][ni] = __builtin_amdgcn_mfma_f32_16x16x32_bf16(
                        af[mi], bfr[ni], acc[mi][ni], 0, 0, 0);
            __builtin_amdgcn_s_setprio(0);
        }
    }

#pragma unroll
    for (int ni = 0; ni < NI; ++ni) {
        int col = n0 + wn + ni * 16 + lr;
        float bvv = bias[col];
#pragma unroll
        for (int mi = 0; mi < MI; ++mi) {
#pragma unroll
            for (int r = 0; r < 4; ++r) {
                int row = m0 + wm + mi * 16 + qd * 4 + r;
                float v = acc[mi][ni][r] + bvv;
                if (RELU) v = fmaxf(v, 0.f);
                if (RESID) v += resid[(size_t)row * N + col];
                if (OUT_BF16)
                    ((unsigned short*)Cout)[(size_t)row * N + col] = f2bf(v);
                else
                    ((float*)Cout)[(size_t)row * N + col] = v;
            }
        }
    }
}

// ---------------------------------------------------------------------------
// Flash attention, MFMA. 1D grid of 2048 blocks, XCD-swizzled so the 4 batch
// blocks sharing the same (h, q-tile) rpb rows land on the same XCD, and the
// longest q-tiles dispatch first. 256 thr = 4 waves, wave w owns q-rows
// [w*16, w*16+16). Q in registers. K/V staged T14-style. V^T XOR-swizzled.
// Causal mask applied only on the diagonal tile (kt == qt).
// __launch_bounds__(256,4): bound 6 forced VGPR 40 -> 1.2GB scratch spill (R2).
// qkv: [M][3072] bf16 (q|k|v each h*64+d). out: [M][1024] bf16.
// ---------------------------------------------------------------------------
__global__ __launch_bounds__(256, 4) void k_attn(
    const unsigned short* __restrict__ qkv, const float* __restrict__ rpb,
    unsigned short* __restrict__ out)
{
    __shared__ unsigned short Ks[64 * 72];
    __shared__ unsigned short Vt[64 * 64];   // element (d,key) at d*64 + (key ^ (swz(d)<<3))
    __shared__ unsigned short Sp[64 * 72];

    // grid swizzle: flat = hi*32 + b*8 + xcd ; g = hi*8 + xcd in 0..511
    int flat = blockIdx.x;
    int xcd = flat & 7, b = (flat >> 3) & 3, hi = flat >> 5;
    int g = hi * 8 + xcd;
    int h = g & 15;
    int qt = 31 - (g >> 4);          // longest blocks first
    int q0 = qt * 64;

    int t = threadIdx.x, lane = t & 63, w = t >> 6;
    int lr = lane & 15, qd = lane >> 4;
    int sr = t >> 2, ss = (t & 3) * 16;
    int bL = b * L_;

    // Q fragments in registers (each wave reads only its own 16 rows)
    bf16x8 aq[2];
    {
        const unsigned short* qsrc =
            qkv + (size_t)(bL + q0 + w * 16 + lr) * 3072 + h * 64 + qd * 8;
        aq[0] = *(const bf16x8*)qsrc;
        aq[1] = *(const bf16x8*)(qsrc + 32);
    }

    f32x4 oacc[4] = {};
    float m_r[4], l_r[4];
#pragma unroll
    for (int r = 0; r < 4; ++r) { m_r[r] = -1e30f; l_r[r] = 0.f; }

    int qrow_base = q0 + w * 16 + qd * 4;
    int ntile = qt + 1;

    // T14 staging registers (K row chunk + V row chunk, 16 elems each)
    ushort8 krA, krB, vrA, vrB;
    {
        const unsigned short* kb_ = qkv + (size_t)(bL + sr) * 3072 + 1024 + h * 64 + ss;
        krA = *(const ushort8*)kb_;  krB = *(const ushort8*)(kb_ + 8);
        vrA = *(const ushort8*)(kb_ + 1024); vrB = *(const ushort8*)(kb_ + 1032);
    }

    for (int kt = 0; kt < ntile; ++kt) {
        int k0 = kt * 64;
        if (kt) __syncthreads();     // all waves done reading previous tile's LDS

        // ---- stage K rows (vectorized, conflict-free) ----
        *(ushort8*)(Ks + sr * 72 + ss)     = krA;
        *(ushort8*)(Ks + sr * 72 + ss + 8) = krB;

        // ---- stage V^T: packed key-pairs into swizzled layout ----
        {
            int role = sr & 1;           // 0: handles d=ss..ss+7, 1: d=ss+8..ss+15
            int srp  = sr & ~1;          // even key of the pair
#pragma unroll
            for (int i = 0; i < 8; ++i) {
                // even-role sends vrB (partner needs it), odd-role sends vrA
                int sendv = role ? (int)(unsigned int)vrA[i] : (int)(unsigned int)vrB[i];
                int got = __shfl_xor(sendv, 4);
                int d = role ? (ss + 8 + i) : (ss + i);
                unsigned short lo = role ? (unsigned short)got : vrA[i]; // key srp
                unsigned short hi = role ? vrB[i] : (unsigned short)got; // key srp+1
                int swz = (d ^ (d >> 3)) & 7;
                unsigned int u = (unsigned int)lo | ((unsigned int)hi << 16);
                *(unsigned int*)(Vt + d * 64 + (srp ^ (swz << 3))) = u;
            }
        }
        __syncthreads();             // tile kt staged

        // ---- prefetch rpb for this tile (issued before next-tile K/V so the
        //      softmax waits vmcnt(4), leaving the K/V loads in flight) ----
        float rv[4][4];
        {
            const float* rpb_base = rpb + ((size_t)h * L_ + qrow_base) * L_ + k0;
#pragma unroll
            for (int r = 0; r < 4; ++r)
#pragma unroll
                for (int nt = 0; nt < 4; ++nt)
                    rv[r][nt] = rpb_base[(size_t)r * L_ + nt * 16 + lr];
        }

        // ---- issue next tile's K/V global loads (land during compute) ----
        if (kt + 1 < ntile) {
            const unsigned short* kb_ =
                qkv + (size_t)(bL + k0 + 64 + sr) * 3072 + 1024 + h * 64 + ss;
            krA = *(const ushort8*)kb_;  krB = *(const ushort8*)(kb_ + 8);
            vrA = *(const ushort8*)(kb_ + 1024); vrB = *(const ushort8*)(kb_ + 1032);
        }

        // ---- S = Q K^T (16 q-rows x 64 keys per wave) ----
        f32x4 sc4[4] = {};
        __builtin_amdgcn_s_setprio(1);
#pragma unroll
        for (int ks = 0; ks < 2; ++ks) {
#pragma unroll
            for (int nt = 0; nt < 4; ++nt) {
                bf16x8 bk8 = *(const bf16x8*)(Ks + (nt * 16 + lr) * 72 + ks * 32 + qd * 8);
                sc4[nt] = __builtin_amdgcn_mfma_f32_16x16x32_bf16(aq[ks], bk8, sc4[nt], 0, 0, 0);
            }
        }
        __builtin_amdgcn_s_setprio(0);

        // ---- online softmax (state replicated over the 16 lanes of each quad) ----
        bool last = (kt == qt);      // only the diagonal tile needs the causal mask
        float pvv[4][4], mx[4];
#pragma unroll
        for (int r = 0; r < 4; ++r) {
            mx[r] = -1e30f;
#pragma unroll
            for (int nt = 0; nt < 4; ++nt) {
                float sv = sc4[nt][r] * 0.125f + rv[r][nt];
                if (last && (k0 + nt * 16 + lr > qrow_base + r)) sv = -1e30f;
                pvv[r][nt] = sv;
                mx[r] = fmaxf(mx[r], sv);
            }
        }
#pragma unroll
        for (int r = 0; r < 4; ++r) {
            mx[r] = fmaxf(mx[r], __shfl_xor(mx[r], 1));
            mx[r] = fmaxf(mx[r], __shfl_xor(mx[r], 2));
            mx[r] = fmaxf(mx[r], __shfl_xor(mx[r], 4));
            mx[r] = fmaxf(mx[r], __shfl_xor(mx[r], 8));
        }
#pragma unroll
        for (int r = 0; r < 4; ++r) {
            float mnew  = fmaxf(m_r[r], mx[r]);
            float alpha = __expf(m_r[r] - mnew);
            float psum = 0.f;
#pragma unroll
            for (int nt = 0; nt < 4; ++nt) {
                float p = __expf(pvv[r][nt] - mnew);
                psum += p;
                Sp[(w * 16 + qd * 4 + r) * 72 + nt * 16 + lr] = f2bf(p);
            }
            psum += __shfl_xor(psum, 1);
            psum += __shfl_xor(psum, 2);
            psum += __shfl_xor(psum, 4);
            psum += __shfl_xor(psum, 8);
            l_r[r] = l_r[r] * alpha + psum;
            m_r[r] = mnew;
            oacc[0][r] *= alpha; oacc[1][r] *= alpha;
            oacc[2][r] *= alpha; oacc[3][r] *= alpha;
        }

        // ---- O += P V  (A = P from Sp, B = swizzled Vt) ----
        __builtin_amdgcn_s_setprio(1);
#pragma unroll
        for (int ks = 0; ks < 2; ++ks) {
            bf16x8 ap = *(const bf16x8*)(Sp + (w * 16 + lr) * 72 + ks * 32 + qd * 8);
#pragma unroll
            for (int dt = 0; dt < 4; ++dt) {
                int d = dt * 16 + lr;
                int swz = (d ^ (d >> 3)) & 7;
                bf16x8 bv8 = *(const bf16x8*)(Vt + d * 64 + ((ks * 32 + qd * 8) ^ (swz << 3)));
                oacc[dt] = __builtin_amdgcn_mfma_f32_16x16x32_bf16(ap, bv8, oacc[dt], 0, 0, 0);
            }
        }
        __builtin_amdgcn_s_setprio(0);
    }

#pragma unroll
    for (int r = 0; r < 4; ++r) {
        float linv = 1.f / l_r[r];
        int qrow = q0 + w * 16 + qd * 4 + r;
        unsigned short* dst = out + (size_t)(bL + qrow) * 1024 + h * 64;
#pragma unroll
        for (int dt = 0; dt < 4; ++dt)
            dst[dt * 16 + lr] = f2bf(oacc[dt][r] * linv);
    }
}

// ---------------------------------------------------------------------------
extern "C" void kernel_launch(void* const* d_in, const int* in_sizes, int n_in,
                              void* d_out, int out_size, void* d_ws, size_t ws_size,
                              hipStream_t stream)
{
    const float* x   = (const float*)d_in[0];
    const float* rpb = (const float*)d_in[1];
    const float* wq  = (const float*)d_in[2];
    const float* bq  = (const float*)d_in[3];
    const float* wk  = (const float*)d_in[4];
    const float* bk  = (const float*)d_in[5];
    const float* wv  = (const float*)d_in[6];
    const float* bv  = (const float*)d_in[7];
    const float* wo  = (const float*)d_in[8];
    const float* bo  = (const float*)d_in[9];
    const float* g1  = (const float*)d_in[10];
    const float* be1 = (const float*)d_in[11];
    const float* g2  = (const float*)d_in[12];
    const float* be2 = (const float*)d_in[13];
    const float* w1  = (const float*)d_in[14];
    const float* bf1 = (const float*)d_in[15];
    const float* w2  = (const float*)d_in[16];
    const float* bf2 = (const float*)d_in[17];
    float* out = (float*)d_out;
    char* ws = (char*)d_ws;

    // workspace layout (bytes); h overlays xn1+qkv (both dead by FFN1)
    unsigned short* xn1   = (unsigned short*)(ws + 0);
    unsigned short* qkv   = (unsigned short*)(ws + 16777216);
    unsigned short* attno = (unsigned short*)(ws + 0);
    unsigned short* hbuf  = (unsigned short*)(ws + 0);
    float*          xmid  = (float*)(ws + 67108864);
    unsigned short* xn2   = (unsigned short*)(ws + 100663296);
    unsigned short* wqkvT = (unsigned short*)(ws + 117440512);
    unsigned short* woT   = (unsigned short*)(ws + 123731968);
    unsigned short* w1T   = (unsigned short*)(ws + 125829120);
    unsigned short* w2T   = (unsigned short*)(ws + 134217728);
    float*          bqkv  = (float*)(ws + 142606336);

    // weight prep (fp32 KxN -> bf16 NxK)
    k_transpose_bf16<<<dim3(16, 16), 256, 0, stream>>>(wq, wqkvT,                1024, 1024);
    k_transpose_bf16<<<dim3(16, 16), 256, 0, stream>>>(wk, wqkvT + 1024 * 1024,  1024, 1024);
    k_transpose_bf16<<<dim3(16, 16), 256, 0, stream>>>(wv, wqkvT + 2048 * 1024,  1024, 1024);
    k_transpose_bf16<<<dim3(16, 16), 256, 0, stream>>>(wo, woT,                  1024, 1024);
    k_transpose_bf16<<<dim3(64, 16), 256, 0, stream>>>(w1, w1T,                  1024, 4096);
    k_transpose_bf16<<<dim3(16, 64), 256, 0, stream>>>(w2, w2T,                  4096, 1024);
    k_concat_bias<<<12, 256, 0, stream>>>(bq, bk, bv, bqkv);

    // LN1 -> xn1 (bf16)
    k_layernorm<<<M_, 256, 0, stream>>>(x, g1, be1, xn1);
    // fused QKV projection: (8192x1024) x (1024x3072): 256x256, 8 waves, 384 wgs
    k_gemm3<256, 256, 2, 4, true, false, false><<<dim3(384), 512, 0, stream>>>(
        xn1, wqkvT, bqkv, nullptr, qkv, M_, 3072, 1024);
    // attention -> attno (bf16, [M][1024])
    k_attn<<<dim3(2048), 256, 0, stream>>>(qkv, rpb, attno);
    // output proj + residual -> xmid (fp32): 128x128, 4 waves, 512 wgs
    k_gemm3<128, 128, 2, 2, false, false, true><<<dim3(512), 256, 0, stream>>>(
        attno, woT, bo, x, xmid, M_, 1024, 1024);
    // LN2 -> xn2 (bf16)
    k_layernorm<<<M_, 256, 0, stream>>>(xmid, g2, be2, xn2);
    // FFN1 + ReLU -> h (bf16): 256x256, 8 waves, 512 wgs
    k_gemm3<256, 256, 2, 4, true, true, false><<<dim3(512), 512, 0, stream>>>(
        xn2, w1T, bf1, nullptr, hbuf, M_, 4096, 1024);
    // FFN2 + residual -> out (fp32): 128x128, 4 waves, 512 wgs, K=4096
    k_gemm3<128, 128, 2, 2, false, false, true><<<dim3(512), 256, 0, stream>>>(
        hbuf, w2T, bf2, xmid, out, M_, 1024, 4096);
}